// Round 1
// baseline (5297.984 us; speedup 1.0000x reference)
//
#include <hip/hip_runtime.h>
#include <hip/hip_bf16.h>
#include <cstddef>

#define NN 50000
#define NE 600000
#define FD 128
#define NL 10
#define BN_EPS 1e-5f
#define NBG ((NN + 63) / 64)   // 782 gemm blocks

// ---------------- dtype detection ----------------
// bn_gamma is all ones: fp32 word0 = 0x3F800000, packed-bf16 word0 = 0x3F803F80.
// edge_index values < 50000: if stored int64, every odd 32-bit word is 0.
__global__ void k_detect(const unsigned int* __restrict__ gamma_raw,
                         const unsigned int* __restrict__ idx_raw,
                         int* __restrict__ flags) {
  if (threadIdx.x == 0 && blockIdx.x == 0) {
    flags[0] = (gamma_raw[0] == 0x3F803F80u) ? 1 : 0;   // 1 = floats are bf16
    int i64 = 1;
    for (int i = 1; i < 64; i += 2)
      if (idx_raw[i] != 0u) i64 = 0;
    flags[1] = i64;                                      // 1 = indices are int64
  }
}

__global__ void k_conv_f(const void* __restrict__ src, float* __restrict__ dst,
                         int n, const int* __restrict__ flags) {
  int i = blockIdx.x * 256 + threadIdx.x;
  if (i >= n) return;
  if (flags[0]) {
    unsigned int u = ((const unsigned short*)src)[i];
    dst[i] = __uint_as_float(u << 16);
  } else {
    dst[i] = ((const float*)src)[i];
  }
}

__global__ void k_conv_i(const void* __restrict__ src, int* __restrict__ dst,
                         int n, const int* __restrict__ flags) {
  int i = blockIdx.x * 256 + threadIdx.x;
  if (i >= n) return;
  if (flags[1]) dst[i] = (int)((const long long*)src)[i];
  else          dst[i] = ((const int*)src)[i];
}

// ---------------- graph preprocessing ----------------
__global__ void k_deg(const int* __restrict__ src, const int* __restrict__ dst,
                      const float* __restrict__ w, float* __restrict__ deg, int m) {
  int e = blockIdx.x * 256 + threadIdx.x;
  if (e >= m) return;
  int s = src[e], d = dst[e];
  float ww = (s == d) ? 0.f : w[e];
  atomicAdd(&deg[s], ww);
}

__global__ void k_dis(float* __restrict__ deg, int n) {
  int i = blockIdx.x * 256 + threadIdx.x;
  if (i >= n) return;
  float d = deg[i];
  deg[i] = (d > 0.f) ? rsqrtf(d) : 0.f;
}

__global__ void k_norm(const int* __restrict__ src, const int* __restrict__ dst,
                       const float* __restrict__ w, const float* __restrict__ dis,
                       float* __restrict__ norm, int* __restrict__ counts, int m) {
  int e = blockIdx.x * 256 + threadIdx.x;
  if (e >= m) return;
  int s = src[e], d = dst[e];
  float ww = (s == d) ? 0.f : w[e];
  norm[e] = -dis[s] * ww * dis[d];
  atomicAdd(&counts[d], 1);
}

__global__ __launch_bounds__(1024) void k_scan(const int* __restrict__ counts,
                                               int* __restrict__ rowptr,
                                               int* __restrict__ cursor, int n) {
  __shared__ int sdata[1024];
  int t = threadIdx.x;
  const int chunk = (n + 1023) / 1024;
  int beg = t * chunk;
  int end = beg + chunk; if (end > n) end = n;
  int s = 0;
  for (int i = beg; i < end; i++) s += counts[i];
  sdata[t] = s;
  __syncthreads();
  for (int off = 1; off < 1024; off <<= 1) {
    int v = sdata[t];
    int add = (t >= off) ? sdata[t - off] : 0;
    __syncthreads();
    sdata[t] = v + add;
    __syncthreads();
  }
  int run = (t == 0) ? 0 : sdata[t - 1];
  for (int i = beg; i < end; i++) {
    int c = counts[i];
    rowptr[i] = run; cursor[i] = run;
    run += c;
  }
  if (beg < n && end == n) rowptr[n] = run;
}

__global__ void k_fill(const int* __restrict__ src, const int* __restrict__ dst,
                       const float* __restrict__ norm, int* __restrict__ cursor,
                       int* __restrict__ csrsrc, float* __restrict__ csrw, int m) {
  int e = blockIdx.x * 256 + threadIdx.x;
  if (e >= m) return;
  int d = dst[e];
  int pos = atomicAdd(&cursor[d], 1);
  csrsrc[pos] = src[e];
  csrw[pos] = norm[e];
}

// ---------------- propagate (pull-mode CSR) ----------------
// out[node][f] = scale * sum_e csrw[e]*h[csrsrc[e]][f]  - (prev ? prev[node][f] : 0)
__global__ __launch_bounds__(256) void k_prop(const float* __restrict__ h,
                                              const float* __restrict__ prev,
                                              const int* __restrict__ rowptr,
                                              const int* __restrict__ csrsrc,
                                              const float* __restrict__ csrw,
                                              float* __restrict__ out,
                                              float scale, int n) {
  int node = blockIdx.x * 2 + (threadIdx.x >> 7);
  int f = threadIdx.x & 127;
  if (node >= n) return;
  int beg = rowptr[node], end = rowptr[node + 1];
  float a = 0.f;
  for (int e = beg; e < end; e++) {
    a = fmaf(csrw[e], h[(size_t)csrsrc[e] * FD + f], a);
  }
  float r = scale * a;
  if (prev) r -= prev[(size_t)node * FD + f];
  out[(size_t)node * FD + f] = r;
}

// ---------------- fused Chebyshev GEMM + bias + relu + BN partials ----------------
__global__ __launch_bounds__(256) void k_gemm(const float* __restrict__ T0,
                                              const float* __restrict__ T1,
                                              const float* __restrict__ T2,
                                              const float* __restrict__ T3,
                                              const float* __restrict__ W,
                                              const float* __restrict__ bias,
                                              float* __restrict__ out,
                                              float* __restrict__ partials, int n) {
  __shared__ float As[32][65];    // transposed A tile: As[k][row]
  __shared__ float Bt[32][129];   // B tile: Bt[k][col]
  const float* Ts[4] = {T0, T1, T2, T3};
  int tx = threadIdx.x & 15;
  int ty = threadIdx.x >> 4;
  int row0 = blockIdx.x * 64;
  float acc[4][8];
#pragma unroll
  for (int m = 0; m < 4; m++)
#pragma unroll
    for (int nn2 = 0; nn2 < 8; nn2++) acc[m][nn2] = 0.f;

  for (int kc = 0; kc < 4; ++kc) {
    const float* T = Ts[kc];
    const float* Wk = W + kc * FD * FD;
    for (int kb = 0; kb < FD; kb += 32) {
#pragma unroll
      for (int it = 0; it < 8; ++it) {
        int e = threadIdx.x + it * 256;
        int r = e >> 5, c = e & 31;
        int row = row0 + r;
        As[c][r] = (row < n) ? T[(size_t)row * FD + kb + c] : 0.f;
      }
#pragma unroll
      for (int it = 0; it < 16; ++it) {
        int e = threadIdx.x + it * 256;
        int r = e >> 7, c = e & 127;
        Bt[r][c] = Wk[(kb + r) * FD + c];
      }
      __syncthreads();
#pragma unroll 4
      for (int k = 0; k < 32; k++) {
        float a[4], b[8];
#pragma unroll
        for (int m = 0; m < 4; m++) a[m] = As[k][m * 16 + ty];
#pragma unroll
        for (int nn2 = 0; nn2 < 8; nn2++) b[nn2] = Bt[k][nn2 * 16 + tx];
#pragma unroll
        for (int m = 0; m < 4; m++)
#pragma unroll
          for (int nn2 = 0; nn2 < 8; nn2++) acc[m][nn2] = fmaf(a[m], b[nn2], acc[m][nn2]);
      }
      __syncthreads();
    }
  }
  // epilogue: bias + relu + store + per-block BN partial sums
  float psum[8], psq[8];
#pragma unroll
  for (int nn2 = 0; nn2 < 8; nn2++) { psum[nn2] = 0.f; psq[nn2] = 0.f; }
#pragma unroll
  for (int m = 0; m < 4; m++) {
    int row = row0 + m * 16 + ty;
    if (row < n) {
#pragma unroll
      for (int nn2 = 0; nn2 < 8; nn2++) {
        int c = nn2 * 16 + tx;
        float v = acc[m][nn2] + bias[c];
        v = fmaxf(v, 0.f);
        out[(size_t)row * FD + c] = v;
        psum[nn2] += v;
        psq[nn2] += v * v;
      }
    }
  }
  __syncthreads();
  float* sred = &As[0][0];   // 2080 floats >= 2048
  float* qred = &Bt[0][0];   // 4128 floats >= 2048
#pragma unroll
  for (int nn2 = 0; nn2 < 8; nn2++) {
    int c = nn2 * 16 + tx;
    sred[ty * 128 + c] = psum[nn2];
    qred[ty * 128 + c] = psq[nn2];
  }
  __syncthreads();
  for (int s = 8; s >= 1; s >>= 1) {
    if (ty < s) {
#pragma unroll
      for (int nn2 = 0; nn2 < 8; nn2++) {
        int c = nn2 * 16 + tx;
        sred[ty * 128 + c] += sred[(ty + s) * 128 + c];
        qred[ty * 128 + c] += qred[(ty + s) * 128 + c];
      }
    }
    __syncthreads();
  }
  if (ty == 0) {
#pragma unroll
    for (int nn2 = 0; nn2 < 8; nn2++) {
      int c = nn2 * 16 + tx;
      partials[(size_t)blockIdx.x * 256 + c] = sred[c];
      partials[(size_t)blockIdx.x * 256 + 128 + c] = qred[c];
    }
  }
}

__global__ void k_bnred(const float* __restrict__ partials, float* __restrict__ stat, int nblocks) {
  int c = blockIdx.x;   // 0..255
  float s = 0.f;
  for (int b = threadIdx.x; b < nblocks; b += 256) s += partials[(size_t)b * 256 + c];
  __shared__ float sd[256];
  sd[threadIdx.x] = s;
  __syncthreads();
  for (int off = 128; off; off >>= 1) {
    if (threadIdx.x < off) sd[threadIdx.x] += sd[threadIdx.x + off];
    __syncthreads();
  }
  if (threadIdx.x == 0) stat[c] = sd[0];
}

__global__ void k_bnapply(const float* __restrict__ in, float* __restrict__ outh,
                          const float* __restrict__ stat, const float* __restrict__ gamma,
                          const float* __restrict__ beta, int total, float invN) {
  int i = blockIdx.x * 256 + threadIdx.x;
  if (i >= total) return;
  int f = i & 127;
  float mean = stat[f] * invN;
  float var = stat[128 + f] * invN - mean * mean;
  float inv = rsqrtf(var + BN_EPS);
  outh[i] = (in[i] - mean) * inv * gamma[f] + beta[f];
}

// ---------------- final linear 128->16 ----------------
__global__ void k_final(const float* __restrict__ h, const float* __restrict__ w,
                        const float* __restrict__ b, void* __restrict__ out,
                        int n, const int* __restrict__ flags) {
  int idx = blockIdx.x * 256 + threadIdx.x;
  if (idx >= n * 16) return;
  int node = idx >> 4, col = idx & 15;
  const float* hr = h + (size_t)node * FD;
  float a = b[col];
#pragma unroll 8
  for (int k = 0; k < FD; k++) a = fmaf(hr[k], w[k * 16 + col], a);
  if (flags[0]) ((__hip_bfloat16*)out)[idx] = __float2bfloat16(a);
  else          ((float*)out)[idx] = a;
}

// ---------------- launcher ----------------
extern "C" void kernel_launch(void* const* d_in, const int* in_sizes, int n_in,
                              void* d_out, int out_size, void* d_ws, size_t ws_size,
                              hipStream_t stream) {
  char* p = (char*)d_ws;
  auto take = [&](size_t bytes) -> void* {
    void* r = (void*)p;
    p += (bytes + 255) & ~size_t(255);
    return r;
  };
  int*   flags  = (int*)  take(64);
  int*   idx32  = (int*)  take(sizeof(int) * 2 * NE);
  float* ewf    = (float*)take(sizeof(float) * NE);
  float* convwf = (float*)take(sizeof(float) * NL * 4 * FD * FD);
  float* convbf = (float*)take(sizeof(float) * NL * FD);
  float* gammaf = (float*)take(sizeof(float) * NL * FD);
  float* betaf  = (float*)take(sizeof(float) * NL * FD);
  float* linwf  = (float*)take(sizeof(float) * FD * 16);
  float* linbf  = (float*)take(sizeof(float) * 16);
  float* deg    = (float*)take(sizeof(float) * NN);
  float* norm   = (float*)take(sizeof(float) * NE);
  int*   counts = (int*)  take(sizeof(int) * NN);
  int*   rowptr = (int*)  take(sizeof(int) * (NN + 1));
  int*   cursor = (int*)  take(sizeof(int) * NN);
  int*   csrsrc = (int*)  take(sizeof(int) * NE);
  float* csrw   = (float*)take(sizeof(float) * NE);
  float* hbuf   = (float*)take(sizeof(float) * (size_t)NN * FD);
  float* t1     = (float*)take(sizeof(float) * (size_t)NN * FD);
  float* t2     = (float*)take(sizeof(float) * (size_t)NN * FD);
  float* t3     = (float*)take(sizeof(float) * (size_t)NN * FD);
  float* accb   = (float*)take(sizeof(float) * (size_t)NN * FD);
  float* partials = (float*)take(sizeof(float) * (size_t)NBG * 256);
  float* stat   = (float*)take(sizeof(float) * 256);

  k_detect<<<1, 64, 0, stream>>>((const unsigned int*)d_in[5], (const unsigned int*)d_in[1], flags);

  k_conv_i<<<(2 * NE + 255) / 256, 256, 0, stream>>>(d_in[1], idx32, 2 * NE, flags);
  k_conv_f<<<(NN * FD + 255) / 256, 256, 0, stream>>>(d_in[0], hbuf, NN * FD, flags);
  k_conv_f<<<(NE + 255) / 256, 256, 0, stream>>>(d_in[2], ewf, NE, flags);
  k_conv_f<<<(NL * 4 * FD * FD + 255) / 256, 256, 0, stream>>>(d_in[3], convwf, NL * 4 * FD * FD, flags);
  k_conv_f<<<(NL * FD + 255) / 256, 256, 0, stream>>>(d_in[4], convbf, NL * FD, flags);
  k_conv_f<<<(NL * FD + 255) / 256, 256, 0, stream>>>(d_in[5], gammaf, NL * FD, flags);
  k_conv_f<<<(NL * FD + 255) / 256, 256, 0, stream>>>(d_in[6], betaf, NL * FD, flags);
  k_conv_f<<<(FD * 16 + 255) / 256, 256, 0, stream>>>(d_in[7], linwf, FD * 16, flags);
  k_conv_f<<<1, 256, 0, stream>>>(d_in[8], linbf, 16, flags);

  hipMemsetAsync(deg, 0, sizeof(float) * NN, stream);
  hipMemsetAsync(counts, 0, sizeof(int) * NN, stream);

  const int* srcI = idx32;
  const int* dstI = idx32 + NE;
  k_deg<<<(NE + 255) / 256, 256, 0, stream>>>(srcI, dstI, ewf, deg, NE);
  k_dis<<<(NN + 255) / 256, 256, 0, stream>>>(deg, NN);
  k_norm<<<(NE + 255) / 256, 256, 0, stream>>>(srcI, dstI, ewf, deg, norm, counts, NE);
  k_scan<<<1, 1024, 0, stream>>>(counts, rowptr, cursor, NN);
  k_fill<<<(NE + 255) / 256, 256, 0, stream>>>(srcI, dstI, norm, cursor, csrsrc, csrw, NE);

  for (int L = 0; L < NL; ++L) {
    const float* W = convwf + (size_t)L * 4 * FD * FD;
    k_prop<<<NN / 2, 256, 0, stream>>>(hbuf, nullptr, rowptr, csrsrc, csrw, t1, 1.f, NN);
    k_prop<<<NN / 2, 256, 0, stream>>>(t1, hbuf, rowptr, csrsrc, csrw, t2, 2.f, NN);
    k_prop<<<NN / 2, 256, 0, stream>>>(t2, t1, rowptr, csrsrc, csrw, t3, 2.f, NN);
    k_gemm<<<NBG, 256, 0, stream>>>(hbuf, t1, t2, t3, W, convbf + L * FD, accb, partials, NN);
    k_bnred<<<256, 256, 0, stream>>>(partials, stat, NBG);
    k_bnapply<<<(NN * FD) / 256, 256, 0, stream>>>(accb, hbuf, stat, gammaf + L * FD, betaf + L * FD, NN * FD, 1.0f / NN);
  }

  k_final<<<(NN * 16 + 255) / 256, 256, 0, stream>>>(hbuf, linwf, linbf, d_out, NN, flags);
}

// Round 2
// 3724.398 us; speedup vs baseline: 1.4225x; 1.4225x over previous
//
#include <hip/hip_runtime.h>
#include <hip/hip_bf16.h>
#include <cstddef>

#define NN 50000
#define NE 600000
#define FD 128
#define NL 10
#define BN_EPS 1e-5f
#define NBG ((NN + 63) / 64)   // 782 gemm blocks

// ---------------- dtype detection ----------------
// bn_gamma is all ones: fp32 word0 = 0x3F800000, packed-bf16 word0 = 0x3F803F80.
// edge_index values < 50000: if stored int64, every odd 32-bit word is 0.
__global__ void k_detect(const unsigned int* __restrict__ gamma_raw,
                         const unsigned int* __restrict__ idx_raw,
                         int* __restrict__ flags) {
  if (threadIdx.x == 0 && blockIdx.x == 0) {
    flags[0] = (gamma_raw[0] == 0x3F803F80u) ? 1 : 0;   // 1 = floats are bf16
    int i64 = 1;
    for (int i = 1; i < 64; i += 2)
      if (idx_raw[i] != 0u) i64 = 0;
    flags[1] = i64;                                      // 1 = indices are int64
  }
}

__global__ void k_conv_f(const void* __restrict__ src, float* __restrict__ dst,
                         int n, const int* __restrict__ flags) {
  int i = blockIdx.x * 256 + threadIdx.x;
  if (i >= n) return;
  if (flags[0]) {
    unsigned int u = ((const unsigned short*)src)[i];
    dst[i] = __uint_as_float(u << 16);
  } else {
    dst[i] = ((const float*)src)[i];
  }
}

__global__ void k_conv_i(const void* __restrict__ src, int* __restrict__ dst,
                         int n, const int* __restrict__ flags) {
  int i = blockIdx.x * 256 + threadIdx.x;
  if (i >= n) return;
  if (flags[1]) dst[i] = (int)((const long long*)src)[i];
  else          dst[i] = ((const int*)src)[i];
}

// ---------------- graph preprocessing ----------------
__global__ void k_deg(const int* __restrict__ src, const int* __restrict__ dst,
                      const float* __restrict__ w, float* __restrict__ deg, int m) {
  int e = blockIdx.x * 256 + threadIdx.x;
  if (e >= m) return;
  int s = src[e], d = dst[e];
  float ww = (s == d) ? 0.f : w[e];
  atomicAdd(&deg[s], ww);
}

__global__ void k_dis(float* __restrict__ deg, int n) {
  int i = blockIdx.x * 256 + threadIdx.x;
  if (i >= n) return;
  float d = deg[i];
  deg[i] = (d > 0.f) ? rsqrtf(d) : 0.f;
}

__global__ void k_norm(const int* __restrict__ src, const int* __restrict__ dst,
                       const float* __restrict__ w, const float* __restrict__ dis,
                       float* __restrict__ norm, int* __restrict__ counts, int m) {
  int e = blockIdx.x * 256 + threadIdx.x;
  if (e >= m) return;
  int s = src[e], d = dst[e];
  float ww = (s == d) ? 0.f : w[e];
  norm[e] = -dis[s] * ww * dis[d];
  atomicAdd(&counts[d], 1);
}

__global__ __launch_bounds__(1024) void k_scan(const int* __restrict__ counts,
                                               int* __restrict__ rowptr,
                                               int* __restrict__ cursor, int n) {
  __shared__ int sdata[1024];
  int t = threadIdx.x;
  const int chunk = (n + 1023) / 1024;
  int beg = t * chunk;
  int end = beg + chunk; if (end > n) end = n;
  int s = 0;
  for (int i = beg; i < end; i++) s += counts[i];
  sdata[t] = s;
  __syncthreads();
  for (int off = 1; off < 1024; off <<= 1) {
    int v = sdata[t];
    int add = (t >= off) ? sdata[t - off] : 0;
    __syncthreads();
    sdata[t] = v + add;
    __syncthreads();
  }
  int run = (t == 0) ? 0 : sdata[t - 1];
  for (int i = beg; i < end; i++) {
    int c = counts[i];
    rowptr[i] = run; cursor[i] = run;
    run += c;
  }
  if (beg < n && end == n) rowptr[n] = run;
}

// pack (src, weight) into int2 so one 8B load fetches both
__global__ void k_fill(const int* __restrict__ src, const int* __restrict__ dst,
                       const float* __restrict__ norm, int* __restrict__ cursor,
                       int2* __restrict__ esw, int m) {
  int e = blockIdx.x * 256 + threadIdx.x;
  if (e >= m) return;
  int d = dst[e];
  int pos = atomicAdd(&cursor[d], 1);
  esw[pos] = make_int2(src[e], __float_as_int(norm[e]));
}

// ---------------- propagate (pull-mode CSR, 8-deep pipelined gathers) ----------------
// out[node][f] = scale * sum_e w[e]*h[src[e]][f]  - (prev ? prev[node][f] : 0)
__global__ __launch_bounds__(256) void k_prop(const float* __restrict__ h,
                                              const float* __restrict__ prev,
                                              const int* __restrict__ rowptr,
                                              const int2* __restrict__ esw,
                                              float* __restrict__ out,
                                              float scale, int n) {
  int node = blockIdx.x * 2 + (threadIdx.x >> 7);
  int f = threadIdx.x & 127;
  if (node >= n) return;
  int beg = rowptr[node], end = rowptr[node + 1];
  float a0 = 0.f, a1 = 0.f;
  for (int e = beg; e < end; e += 8) {
    // load 8 edge records (uniform addresses within the node's threads);
    // clamp OOB to last edge and zero its weight -> uniform pipeline, no tail loop
    int   s[8];
    float w[8];
#pragma unroll
    for (int j = 0; j < 8; j++) {
      int ee = e + j;
      int ec = (ee < end) ? ee : (end - 1);
      int2 m = esw[ec];
      s[j] = m.x;
      w[j] = (ee < end) ? __int_as_float(m.y) : 0.f;
    }
    // 8 independent gathers issue together; fmas retire them in order
    float g[8];
#pragma unroll
    for (int j = 0; j < 8; j++) g[j] = h[(size_t)s[j] * FD + f];
#pragma unroll
    for (int j = 0; j < 8; j += 2) {
      a0 = fmaf(w[j], g[j], a0);
      a1 = fmaf(w[j + 1], g[j + 1], a1);
    }
  }
  float r = scale * (a0 + a1);
  if (prev) r -= prev[(size_t)node * FD + f];
  out[(size_t)node * FD + f] = r;
}

// ---------------- fused Chebyshev GEMM + bias + relu + BN partials ----------------
__global__ __launch_bounds__(256) void k_gemm(const float* __restrict__ T0,
                                              const float* __restrict__ T1,
                                              const float* __restrict__ T2,
                                              const float* __restrict__ T3,
                                              const float* __restrict__ W,
                                              const float* __restrict__ bias,
                                              float* __restrict__ out,
                                              float* __restrict__ partials, int n) {
  __shared__ float As[32][65];    // transposed A tile: As[k][row]
  __shared__ float Bt[32][129];   // B tile: Bt[k][col]
  const float* Ts[4] = {T0, T1, T2, T3};
  int tx = threadIdx.x & 15;
  int ty = threadIdx.x >> 4;
  int row0 = blockIdx.x * 64;
  float acc[4][8];
#pragma unroll
  for (int m = 0; m < 4; m++)
#pragma unroll
    for (int nn2 = 0; nn2 < 8; nn2++) acc[m][nn2] = 0.f;

  for (int kc = 0; kc < 4; ++kc) {
    const float* T = Ts[kc];
    const float* Wk = W + kc * FD * FD;
    for (int kb = 0; kb < FD; kb += 32) {
#pragma unroll
      for (int it = 0; it < 8; ++it) {
        int e = threadIdx.x + it * 256;
        int r = e >> 5, c = e & 31;
        int row = row0 + r;
        As[c][r] = (row < n) ? T[(size_t)row * FD + kb + c] : 0.f;
      }
#pragma unroll
      for (int it = 0; it < 16; ++it) {
        int e = threadIdx.x + it * 256;
        int r = e >> 7, c = e & 127;
        Bt[r][c] = Wk[(kb + r) * FD + c];
      }
      __syncthreads();
#pragma unroll 4
      for (int k = 0; k < 32; k++) {
        float a[4], b[8];
#pragma unroll
        for (int m = 0; m < 4; m++) a[m] = As[k][m * 16 + ty];
#pragma unroll
        for (int nn2 = 0; nn2 < 8; nn2++) b[nn2] = Bt[k][nn2 * 16 + tx];
#pragma unroll
        for (int m = 0; m < 4; m++)
#pragma unroll
          for (int nn2 = 0; nn2 < 8; nn2++) acc[m][nn2] = fmaf(a[m], b[nn2], acc[m][nn2]);
      }
      __syncthreads();
    }
  }
  // epilogue: bias + relu + store + per-block BN partial sums
  float psum[8], psq[8];
#pragma unroll
  for (int nn2 = 0; nn2 < 8; nn2++) { psum[nn2] = 0.f; psq[nn2] = 0.f; }
#pragma unroll
  for (int m = 0; m < 4; m++) {
    int row = row0 + m * 16 + ty;
    if (row < n) {
#pragma unroll
      for (int nn2 = 0; nn2 < 8; nn2++) {
        int c = nn2 * 16 + tx;
        float v = acc[m][nn2] + bias[c];
        v = fmaxf(v, 0.f);
        out[(size_t)row * FD + c] = v;
        psum[nn2] += v;
        psq[nn2] += v * v;
      }
    }
  }
  __syncthreads();
  float* sred = &As[0][0];   // 2080 floats >= 2048
  float* qred = &Bt[0][0];   // 4128 floats >= 2048
#pragma unroll
  for (int nn2 = 0; nn2 < 8; nn2++) {
    int c = nn2 * 16 + tx;
    sred[ty * 128 + c] = psum[nn2];
    qred[ty * 128 + c] = psq[nn2];
  }
  __syncthreads();
  for (int s = 8; s >= 1; s >>= 1) {
    if (ty < s) {
#pragma unroll
      for (int nn2 = 0; nn2 < 8; nn2++) {
        int c = nn2 * 16 + tx;
        sred[ty * 128 + c] += sred[(ty + s) * 128 + c];
        qred[ty * 128 + c] += qred[(ty + s) * 128 + c];
      }
    }
    __syncthreads();
  }
  if (ty == 0) {
#pragma unroll
    for (int nn2 = 0; nn2 < 8; nn2++) {
      int c = nn2 * 16 + tx;
      partials[(size_t)blockIdx.x * 256 + c] = sred[c];
      partials[(size_t)blockIdx.x * 256 + 128 + c] = qred[c];
    }
  }
}

__global__ void k_bnred(const float* __restrict__ partials, float* __restrict__ stat, int nblocks) {
  int c = blockIdx.x;   // 0..255
  float s = 0.f;
  for (int b = threadIdx.x; b < nblocks; b += 256) s += partials[(size_t)b * 256 + c];
  __shared__ float sd[256];
  sd[threadIdx.x] = s;
  __syncthreads();
  for (int off = 128; off; off >>= 1) {
    if (threadIdx.x < off) sd[threadIdx.x] += sd[threadIdx.x + off];
    __syncthreads();
  }
  if (threadIdx.x == 0) stat[c] = sd[0];
}

__global__ void k_bnapply(const float* __restrict__ in, float* __restrict__ outh,
                          const float* __restrict__ stat, const float* __restrict__ gamma,
                          const float* __restrict__ beta, int total, float invN) {
  int i = blockIdx.x * 256 + threadIdx.x;
  if (i >= total) return;
  int f = i & 127;
  float mean = stat[f] * invN;
  float var = stat[128 + f] * invN - mean * mean;
  float inv = rsqrtf(var + BN_EPS);
  outh[i] = (in[i] - mean) * inv * gamma[f] + beta[f];
}

// ---------------- final linear 128->16 ----------------
__global__ void k_final(const float* __restrict__ h, const float* __restrict__ w,
                        const float* __restrict__ b, void* __restrict__ out,
                        int n, const int* __restrict__ flags) {
  int idx = blockIdx.x * 256 + threadIdx.x;
  if (idx >= n * 16) return;
  int node = idx >> 4, col = idx & 15;
  const float* hr = h + (size_t)node * FD;
  float a = b[col];
#pragma unroll 8
  for (int k = 0; k < FD; k++) a = fmaf(hr[k], w[k * 16 + col], a);
  if (flags[0]) ((__hip_bfloat16*)out)[idx] = __float2bfloat16(a);
  else          ((float*)out)[idx] = a;
}

// ---------------- launcher ----------------
extern "C" void kernel_launch(void* const* d_in, const int* in_sizes, int n_in,
                              void* d_out, int out_size, void* d_ws, size_t ws_size,
                              hipStream_t stream) {
  char* p = (char*)d_ws;
  auto take = [&](size_t bytes) -> void* {
    void* r = (void*)p;
    p += (bytes + 255) & ~size_t(255);
    return r;
  };
  int*   flags  = (int*)  take(64);
  int*   idx32  = (int*)  take(sizeof(int) * 2 * NE);
  float* ewf    = (float*)take(sizeof(float) * NE);
  float* convwf = (float*)take(sizeof(float) * NL * 4 * FD * FD);
  float* convbf = (float*)take(sizeof(float) * NL * FD);
  float* gammaf = (float*)take(sizeof(float) * NL * FD);
  float* betaf  = (float*)take(sizeof(float) * NL * FD);
  float* linwf  = (float*)take(sizeof(float) * FD * 16);
  float* linbf  = (float*)take(sizeof(float) * 16);
  float* deg    = (float*)take(sizeof(float) * NN);
  float* norm   = (float*)take(sizeof(float) * NE);
  int*   counts = (int*)  take(sizeof(int) * NN);
  int*   rowptr = (int*)  take(sizeof(int) * (NN + 1));
  int*   cursor = (int*)  take(sizeof(int) * NN);
  int2*  esw    = (int2*) take(sizeof(int2) * NE);
  float* hbuf   = (float*)take(sizeof(float) * (size_t)NN * FD);
  float* t1     = (float*)take(sizeof(float) * (size_t)NN * FD);
  float* t2     = (float*)take(sizeof(float) * (size_t)NN * FD);
  float* t3     = (float*)take(sizeof(float) * (size_t)NN * FD);
  float* accb   = (float*)take(sizeof(float) * (size_t)NN * FD);
  float* partials = (float*)take(sizeof(float) * (size_t)NBG * 256);
  float* stat   = (float*)take(sizeof(float) * 256);

  k_detect<<<1, 64, 0, stream>>>((const unsigned int*)d_in[5], (const unsigned int*)d_in[1], flags);

  k_conv_i<<<(2 * NE + 255) / 256, 256, 0, stream>>>(d_in[1], idx32, 2 * NE, flags);
  k_conv_f<<<(NN * FD + 255) / 256, 256, 0, stream>>>(d_in[0], hbuf, NN * FD, flags);
  k_conv_f<<<(NE + 255) / 256, 256, 0, stream>>>(d_in[2], ewf, NE, flags);
  k_conv_f<<<(NL * 4 * FD * FD + 255) / 256, 256, 0, stream>>>(d_in[3], convwf, NL * 4 * FD * FD, flags);
  k_conv_f<<<(NL * FD + 255) / 256, 256, 0, stream>>>(d_in[4], convbf, NL * FD, flags);
  k_conv_f<<<(NL * FD + 255) / 256, 256, 0, stream>>>(d_in[5], gammaf, NL * FD, flags);
  k_conv_f<<<(NL * FD + 255) / 256, 256, 0, stream>>>(d_in[6], betaf, NL * FD, flags);
  k_conv_f<<<(FD * 16 + 255) / 256, 256, 0, stream>>>(d_in[7], linwf, FD * 16, flags);
  k_conv_f<<<1, 256, 0, stream>>>(d_in[8], linbf, 16, flags);

  hipMemsetAsync(deg, 0, sizeof(float) * NN, stream);
  hipMemsetAsync(counts, 0, sizeof(int) * NN, stream);

  const int* srcI = idx32;
  const int* dstI = idx32 + NE;
  k_deg<<<(NE + 255) / 256, 256, 0, stream>>>(srcI, dstI, ewf, deg, NE);
  k_dis<<<(NN + 255) / 256, 256, 0, stream>>>(deg, NN);
  k_norm<<<(NE + 255) / 256, 256, 0, stream>>>(srcI, dstI, ewf, deg, norm, counts, NE);
  k_scan<<<1, 1024, 0, stream>>>(counts, rowptr, cursor, NN);
  k_fill<<<(NE + 255) / 256, 256, 0, stream>>>(srcI, dstI, norm, cursor, esw, NE);

  for (int L = 0; L < NL; ++L) {
    const float* W = convwf + (size_t)L * 4 * FD * FD;
    k_prop<<<NN / 2, 256, 0, stream>>>(hbuf, nullptr, rowptr, esw, t1, 1.f, NN);
    k_prop<<<NN / 2, 256, 0, stream>>>(t1, hbuf, rowptr, esw, t2, 2.f, NN);
    k_prop<<<NN / 2, 256, 0, stream>>>(t2, t1, rowptr, esw, t3, 2.f, NN);
    k_gemm<<<NBG, 256, 0, stream>>>(hbuf, t1, t2, t3, W, convbf + L * FD, accb, partials, NN);
    k_bnred<<<256, 256, 0, stream>>>(partials, stat, NBG);
    k_bnapply<<<(NN * FD) / 256, 256, 0, stream>>>(accb, hbuf, stat, gammaf + L * FD, betaf + L * FD, NN * FD, 1.0f / NN);
  }

  k_final<<<(NN * 16 + 255) / 256, 256, 0, stream>>>(hbuf, linwf, linbf, d_out, NN, flags);
}

// Round 3
// 1636.285 us; speedup vs baseline: 3.2378x; 2.2761x over previous
//
#include <hip/hip_runtime.h>
#include <hip/hip_bf16.h>
#include <cstddef>

#define NN 50000
#define NE 600000
#define FD 128
#define NL 10
#define BN_EPS 1e-5f
#define NBG ((NN + 127) / 128)   // 391 gemm blocks

typedef _Float16 f16x8 __attribute__((ext_vector_type(8)));
typedef _Float16 f16x2 __attribute__((ext_vector_type(2)));
typedef float f32x4 __attribute__((ext_vector_type(4)));

// ---------------- dtype detection ----------------
__global__ void k_detect(const unsigned int* __restrict__ gamma_raw,
                         const unsigned int* __restrict__ idx_raw,
                         int* __restrict__ flags) {
  if (threadIdx.x == 0 && blockIdx.x == 0) {
    flags[0] = (gamma_raw[0] == 0x3F803F80u) ? 1 : 0;   // 1 = floats are bf16
    int i64 = 1;
    for (int i = 1; i < 64; i += 2)
      if (idx_raw[i] != 0u) i64 = 0;
    flags[1] = i64;                                      // 1 = indices are int64
  }
}

__device__ __forceinline__ float ld_f(const void* src, int i, int isbf) {
  if (isbf) {
    unsigned int u = ((const unsigned short*)src)[i];
    return __uint_as_float(u << 16);
  }
  return ((const float*)src)[i];
}

__global__ void k_conv_f(const void* __restrict__ src, float* __restrict__ dst,
                         int n, const int* __restrict__ flags) {
  int i = blockIdx.x * 256 + threadIdx.x;
  if (i >= n) return;
  dst[i] = ld_f(src, i, flags[0]);
}

__global__ void k_conv_i(const void* __restrict__ src, int* __restrict__ dst,
                         int n, const int* __restrict__ flags) {
  int i = blockIdx.x * 256 + threadIdx.x;
  if (i >= n) return;
  if (flags[1]) dst[i] = (int)((const long long*)src)[i];
  else          dst[i] = ((const int*)src)[i];
}

// x -> fp16 h (packed as uint half2 pairs), n2 = count of pairs
__global__ void k_conv_h(const void* __restrict__ src, unsigned int* __restrict__ dst,
                         int n2, const int* __restrict__ flags) {
  int i = blockIdx.x * 256 + threadIdx.x;
  if (i >= n2) return;
  int isbf = flags[0];
  f16x2 p;
  p.x = (_Float16)ld_f(src, i * 2, isbf);
  p.y = (_Float16)ld_f(src, i * 2 + 1, isbf);
  dst[i] = *(unsigned int*)&p;
}

// conv_w [10][4][128][128] -> fp16 tiled Wt[(L*16+s)*4096 + n*32 + kk]
//   where s = kc*4+kb, source element = W[L][kc][kb*32+kk][n]
__global__ void k_prepW(const void* __restrict__ src, unsigned short* __restrict__ dst,
                        const int* __restrict__ flags) {
  int tid = blockIdx.x * 256 + threadIdx.x;   // < 655360
  if (tid >= NL * 16 * 4096) return;
  int L = tid >> 16;
  int r16 = tid & 65535;
  int s = r16 >> 12;
  int r = r16 & 4095;
  int n = r >> 5, kk = r & 31;
  int kc = s >> 2, kb = s & 3;
  int srcIdx = ((L * 4 + kc) * FD + (kb * 32 + kk)) * FD + n;
  _Float16 v = (_Float16)ld_f(src, srcIdx, flags[0]);
  dst[tid] = *(unsigned short*)&v;
}

// ---------------- graph preprocessing ----------------
__global__ void k_deg(const int* __restrict__ src, const int* __restrict__ dst,
                      const float* __restrict__ w, float* __restrict__ deg, int m) {
  int e = blockIdx.x * 256 + threadIdx.x;
  if (e >= m) return;
  int s = src[e], d = dst[e];
  float ww = (s == d) ? 0.f : w[e];
  atomicAdd(&deg[s], ww);
}

__global__ void k_dis(float* __restrict__ deg, int n) {
  int i = blockIdx.x * 256 + threadIdx.x;
  if (i >= n) return;
  float d = deg[i];
  deg[i] = (d > 0.f) ? rsqrtf(d) : 0.f;
}

__global__ void k_norm(const int* __restrict__ src, const int* __restrict__ dst,
                       const float* __restrict__ w, const float* __restrict__ dis,
                       float* __restrict__ norm, int* __restrict__ counts, int m) {
  int e = blockIdx.x * 256 + threadIdx.x;
  if (e >= m) return;
  int s = src[e], d = dst[e];
  float ww = (s == d) ? 0.f : w[e];
  norm[e] = -dis[s] * ww * dis[d];
  atomicAdd(&counts[d], 1);
}

__global__ __launch_bounds__(1024) void k_scan(const int* __restrict__ counts,
                                               int* __restrict__ rowptr,
                                               int* __restrict__ cursor, int n) {
  __shared__ int sdata[1024];
  int t = threadIdx.x;
  const int chunk = (n + 1023) / 1024;
  int beg = t * chunk;
  int end = beg + chunk; if (end > n) end = n;
  int s = 0;
  for (int i = beg; i < end; i++) s += counts[i];
  sdata[t] = s;
  __syncthreads();
  for (int off = 1; off < 1024; off <<= 1) {
    int v = sdata[t];
    int add = (t >= off) ? sdata[t - off] : 0;
    __syncthreads();
    sdata[t] = v + add;
    __syncthreads();
  }
  int run = (t == 0) ? 0 : sdata[t - 1];
  for (int i = beg; i < end; i++) {
    int c = counts[i];
    rowptr[i] = run; cursor[i] = run;
    run += c;
  }
  if (beg < n && end == n) rowptr[n] = run;
}

__global__ void k_fill(const int* __restrict__ src, const int* __restrict__ dst,
                       const float* __restrict__ norm, int* __restrict__ cursor,
                       int2* __restrict__ esw, int m) {
  int e = blockIdx.x * 256 + threadIdx.x;
  if (e >= m) return;
  int d = dst[e];
  int pos = atomicAdd(&cursor[d], 1);
  esw[pos] = make_int2(src[e], __float_as_int(norm[e]));
}

// ---------------- propagate (fp16 gathers, 8-deep pipeline) ----------------
// h packed as uint half2: h32[node*64 + f2]
__global__ __launch_bounds__(256) void k_prop(const unsigned int* __restrict__ h32,
                                              const unsigned int* __restrict__ prev32,
                                              const int* __restrict__ rowptr,
                                              const int2* __restrict__ esw,
                                              unsigned int* __restrict__ out32,
                                              float scale, int n) {
  int node = blockIdx.x * 4 + (threadIdx.x >> 6);
  int f2 = threadIdx.x & 63;
  if (node >= n) return;
  int beg = rowptr[node], end = rowptr[node + 1];
  float a0 = 0.f, a1 = 0.f;
  for (int e = beg; e < end; e += 8) {
    int   s[8];
    float w[8];
#pragma unroll
    for (int j = 0; j < 8; j++) {
      int ee = e + j;
      int ec = (ee < end) ? ee : (end - 1);
      int2 m = esw[ec];
      s[j] = m.x;
      w[j] = (ee < end) ? __int_as_float(m.y) : 0.f;
    }
    unsigned int g[8];
#pragma unroll
    for (int j = 0; j < 8; j++) g[j] = h32[(size_t)s[j] * 64 + f2];
#pragma unroll
    for (int j = 0; j < 8; j++) {
      f16x2 u = *(f16x2*)&g[j];
      a0 = fmaf(w[j], (float)u.x, a0);
      a1 = fmaf(w[j], (float)u.y, a1);
    }
  }
  float r0 = scale * a0, r1 = scale * a1;
  if (prev32) {
    f16x2 pv = *(f16x2*)&prev32[(size_t)node * 64 + f2];
    r0 -= (float)pv.x;
    r1 -= (float)pv.y;
  }
  f16x2 o; o.x = (_Float16)r0; o.y = (_Float16)r1;
  out32[(size_t)node * 64 + f2] = *(unsigned int*)&o;
}

// ---------------- MFMA fp16 GEMM: C = [T0|T1|T2|T3] @ Wt, + bias + relu + BN partials ----
__global__ __launch_bounds__(256) void k_gemm(const unsigned short* __restrict__ T0h,
                                              const unsigned short* __restrict__ T1h,
                                              const unsigned short* __restrict__ T2h,
                                              const unsigned short* __restrict__ T3h,
                                              const unsigned short* __restrict__ Wt,
                                              const float* __restrict__ bias,
                                              float* __restrict__ out,
                                              float* __restrict__ partials, int n) {
  __shared__ unsigned short ldsB[2][128 * 40];   // stride 40 shorts = 80B (16B aligned, staircase banks)
  __shared__ float lps[4][128], lqs[4][128];
  int tid = threadIdx.x;
  int wid = tid >> 6, lane = tid & 63;
  int ln = lane & 15, kg = lane >> 4;
  int r0 = blockIdx.x * 128 + wid * 32;

  f32x4 acc[2][8];
#pragma unroll
  for (int rb = 0; rb < 2; rb++)
#pragma unroll
    for (int nb = 0; nb < 8; nb++) acc[rb][nb] = (f32x4){0.f, 0.f, 0.f, 0.f};

  // stage step 0
  {
    const uint4* g = (const uint4*)(Wt);
    uint4 a = g[tid], b = g[tid + 256];
    *(uint4*)&ldsB[0][(tid >> 2) * 40 + (tid & 3) * 8] = a;
    *(uint4*)&ldsB[0][((tid >> 2) + 64) * 40 + (tid & 3) * 8] = b;
  }
  __syncthreads();

  int rowA0 = r0 + ln;       if (rowA0 >= n) rowA0 = n - 1;
  int rowA1 = r0 + 16 + ln;  if (rowA1 >= n) rowA1 = n - 1;

#pragma unroll
  for (int kc = 0; kc < 4; ++kc) {
    const unsigned short* T = (kc == 0) ? T0h : (kc == 1) ? T1h : (kc == 2) ? T2h : T3h;
#pragma unroll
    for (int kb = 0; kb < 4; ++kb) {
      const int s = kc * 4 + kb;
      const int cur = s & 1;
      uint4 st0, st1;
      if (s < 15) {           // issue next-tile staging loads early
        const uint4* g = (const uint4*)(Wt + (s + 1) * 4096);
        st0 = g[tid]; st1 = g[tid + 256];
      }
      // A fragments straight from global (L2-resident rows)
      f16x8 a0 = *(const f16x8*)(T + (size_t)rowA0 * FD + kb * 32 + kg * 8);
      f16x8 a1 = *(const f16x8*)(T + (size_t)rowA1 * FD + kb * 32 + kg * 8);
      // B fragments from LDS
      f16x8 bf[8];
#pragma unroll
      for (int nb = 0; nb < 8; nb++)
        bf[nb] = *(const f16x8*)&ldsB[cur][(nb * 16 + ln) * 40 + kg * 8];
#pragma unroll
      for (int nb = 0; nb < 8; nb++) {
        acc[0][nb] = __builtin_amdgcn_mfma_f32_16x16x32_f16(a0, bf[nb], acc[0][nb], 0, 0, 0);
        acc[1][nb] = __builtin_amdgcn_mfma_f32_16x16x32_f16(a1, bf[nb], acc[1][nb], 0, 0, 0);
      }
      if (s < 15) {
        *(uint4*)&ldsB[cur ^ 1][(tid >> 2) * 40 + (tid & 3) * 8] = st0;
        *(uint4*)&ldsB[cur ^ 1][((tid >> 2) + 64) * 40 + (tid & 3) * 8] = st1;
      }
      __syncthreads();
    }
  }

  // epilogue: bias + relu + store fp32 + BN partial sums
  float psum[8], psq[8];
#pragma unroll
  for (int nb = 0; nb < 8; nb++) { psum[nb] = 0.f; psq[nb] = 0.f; }
#pragma unroll
  for (int rb = 0; rb < 2; rb++) {
#pragma unroll
    for (int nb = 0; nb < 8; nb++) {
      int col = nb * 16 + ln;
      float bs = bias[col];
#pragma unroll
      for (int r = 0; r < 4; r++) {
        int row = r0 + rb * 16 + kg * 4 + r;
        if (row < n) {
          float v = acc[rb][nb][r] + bs;
          v = fmaxf(v, 0.f);
          out[(size_t)row * FD + col] = v;
          psum[nb] += v;
          psq[nb] += v * v;
        }
      }
    }
  }
#pragma unroll
  for (int nb = 0; nb < 8; nb++) {
    float sv = psum[nb], qv = psq[nb];
    sv += __shfl_xor(sv, 16); sv += __shfl_xor(sv, 32);
    qv += __shfl_xor(qv, 16); qv += __shfl_xor(qv, 32);
    if (kg == 0) { lps[wid][nb * 16 + ln] = sv; lqs[wid][nb * 16 + ln] = qv; }
  }
  __syncthreads();
  if (tid < 128) {
    float sv = lps[0][tid] + lps[1][tid] + lps[2][tid] + lps[3][tid];
    partials[(size_t)blockIdx.x * 256 + tid] = sv;
  } else {
    int c = tid - 128;
    float qv = lqs[0][c] + lqs[1][c] + lqs[2][c] + lqs[3][c];
    partials[(size_t)blockIdx.x * 256 + 128 + c] = qv;
  }
}

__global__ void k_bnred(const float* __restrict__ partials, float* __restrict__ stat, int nblocks) {
  int c = blockIdx.x;   // 0..255
  float s = 0.f;
  for (int b = threadIdx.x; b < nblocks; b += 256) s += partials[(size_t)b * 256 + c];
  __shared__ float sd[256];
  sd[threadIdx.x] = s;
  __syncthreads();
  for (int off = 128; off; off >>= 1) {
    if (threadIdx.x < off) sd[threadIdx.x] += sd[threadIdx.x + off];
    __syncthreads();
  }
  if (threadIdx.x == 0) stat[c] = sd[0];
}

// accb fp32 -> h fp16 (half2-packed)
__global__ void k_bnapply(const float* __restrict__ in, unsigned int* __restrict__ outh,
                          const float* __restrict__ stat, const float* __restrict__ gamma,
                          const float* __restrict__ beta, int n2, float invN) {
  int i = blockIdx.x * 256 + threadIdx.x;
  if (i >= n2) return;
  int f0 = (i & 63) * 2;
  float2 v = ((const float2*)in)[i];
  float m0 = stat[f0] * invN;
  float m1 = stat[f0 + 1] * invN;
  float iv0 = rsqrtf(stat[128 + f0] * invN - m0 * m0 + BN_EPS);
  float iv1 = rsqrtf(stat[128 + f0 + 1] * invN - m1 * m1 + BN_EPS);
  float r0 = (v.x - m0) * iv0 * gamma[f0] + beta[f0];
  float r1 = (v.y - m1) * iv1 * gamma[f0 + 1] + beta[f0 + 1];
  f16x2 o; o.x = (_Float16)r0; o.y = (_Float16)r1;
  outh[i] = *(unsigned int*)&o;
}

// ---------------- final linear 128->16, one node per thread ----------------
__global__ void k_final(const unsigned short* __restrict__ h, const float* __restrict__ w,
                        const float* __restrict__ b, void* __restrict__ out,
                        int n, const int* __restrict__ flags) {
  __shared__ float lw[2048];
  for (int i = threadIdx.x; i < 2048; i += 256) lw[i] = w[i];
  __syncthreads();
  int node = blockIdx.x * 256 + threadIdx.x;
  if (node >= n) return;
  float acc[16];
#pragma unroll
  for (int c = 0; c < 16; c++) acc[c] = b[c];
  const f16x8* hr = (const f16x8*)(h + (size_t)node * FD);
#pragma unroll 2
  for (int k8 = 0; k8 < 16; k8++) {
    f16x8 hv = hr[k8];
#pragma unroll
    for (int j = 0; j < 8; j++) {
      float x = (float)hv[j];
#pragma unroll
      for (int c = 0; c < 16; c++) acc[c] = fmaf(x, lw[(k8 * 8 + j) * 16 + c], acc[c]);
    }
  }
  int isbf = flags[0];
  for (int c = 0; c < 16; c++) {
    int idx = node * 16 + c;
    if (isbf) ((__hip_bfloat16*)out)[idx] = __float2bfloat16(acc[c]);
    else      ((float*)out)[idx] = acc[c];
  }
}

// ---------------- launcher ----------------
extern "C" void kernel_launch(void* const* d_in, const int* in_sizes, int n_in,
                              void* d_out, int out_size, void* d_ws, size_t ws_size,
                              hipStream_t stream) {
  char* p = (char*)d_ws;
  auto take = [&](size_t bytes) -> void* {
    void* r = (void*)p;
    p += (bytes + 255) & ~size_t(255);
    return r;
  };
  int*   flags  = (int*)  take(64);
  int*   idx32  = (int*)  take(sizeof(int) * 2 * NE);
  float* ewf    = (float*)take(sizeof(float) * NE);
  unsigned short* wtws = (unsigned short*)take(sizeof(short) * NL * 16 * 4096);
  float* convbf = (float*)take(sizeof(float) * NL * FD);
  float* gammaf = (float*)take(sizeof(float) * NL * FD);
  float* betaf  = (float*)take(sizeof(float) * NL * FD);
  float* linwf  = (float*)take(sizeof(float) * FD * 16);
  float* linbf  = (float*)take(sizeof(float) * 16);
  float* deg    = (float*)take(sizeof(float) * NN);
  float* norm   = (float*)take(sizeof(float) * NE);
  int*   counts = (int*)  take(sizeof(int) * NN);
  int*   rowptr = (int*)  take(sizeof(int) * (NN + 1));
  int*   cursor = (int*)  take(sizeof(int) * NN);
  int2*  esw    = (int2*) take(sizeof(int2) * NE);
  unsigned int* hbuf = (unsigned int*)take(sizeof(int) * (size_t)NN * 64);
  unsigned int* t1   = (unsigned int*)take(sizeof(int) * (size_t)NN * 64);
  unsigned int* t2   = (unsigned int*)take(sizeof(int) * (size_t)NN * 64);
  unsigned int* t3   = (unsigned int*)take(sizeof(int) * (size_t)NN * 64);
  float* accb   = (float*)take(sizeof(float) * (size_t)NN * FD);
  float* partials = (float*)take(sizeof(float) * (size_t)NBG * 256);
  float* stat   = (float*)take(sizeof(float) * 256);

  k_detect<<<1, 64, 0, stream>>>((const unsigned int*)d_in[5], (const unsigned int*)d_in[1], flags);

  k_conv_i<<<(2 * NE + 255) / 256, 256, 0, stream>>>(d_in[1], idx32, 2 * NE, flags);
  k_conv_h<<<(NN * 64 + 255) / 256, 256, 0, stream>>>(d_in[0], hbuf, NN * 64, flags);
  k_conv_f<<<(NE + 255) / 256, 256, 0, stream>>>(d_in[2], ewf, NE, flags);
  k_prepW<<<(NL * 16 * 4096 + 255) / 256, 256, 0, stream>>>(d_in[3], wtws, flags);
  k_conv_f<<<(NL * FD + 255) / 256, 256, 0, stream>>>(d_in[4], convbf, NL * FD, flags);
  k_conv_f<<<(NL * FD + 255) / 256, 256, 0, stream>>>(d_in[6], betaf, NL * FD, flags);
  k_conv_f<<<(NL * FD + 255) / 256, 256, 0, stream>>>(d_in[5], gammaf, NL * FD, flags);
  k_conv_f<<<(FD * 16 + 255) / 256, 256, 0, stream>>>(d_in[7], linwf, FD * 16, flags);
  k_conv_f<<<1, 256, 0, stream>>>(d_in[8], linbf, 16, flags);

  hipMemsetAsync(deg, 0, sizeof(float) * NN, stream);
  hipMemsetAsync(counts, 0, sizeof(int) * NN, stream);

  const int* srcI = idx32;
  const int* dstI = idx32 + NE;
  k_deg<<<(NE + 255) / 256, 256, 0, stream>>>(srcI, dstI, ewf, deg, NE);
  k_dis<<<(NN + 255) / 256, 256, 0, stream>>>(deg, NN);
  k_norm<<<(NE + 255) / 256, 256, 0, stream>>>(srcI, dstI, ewf, deg, norm, counts, NE);
  k_scan<<<1, 1024, 0, stream>>>(counts, rowptr, cursor, NN);
  k_fill<<<(NE + 255) / 256, 256, 0, stream>>>(srcI, dstI, norm, cursor, esw, NE);

  for (int L = 0; L < NL; ++L) {
    const unsigned short* Wt = wtws + (size_t)L * 16 * 4096;
    k_prop<<<NN / 4, 256, 0, stream>>>(hbuf, nullptr, rowptr, esw, t1, 1.f, NN);
    k_prop<<<NN / 4, 256, 0, stream>>>(t1, hbuf, rowptr, esw, t2, 2.f, NN);
    k_prop<<<NN / 4, 256, 0, stream>>>(t2, t1, rowptr, esw, t3, 2.f, NN);
    k_gemm<<<NBG, 256, 0, stream>>>((const unsigned short*)hbuf, (const unsigned short*)t1,
                                    (const unsigned short*)t2, (const unsigned short*)t3,
                                    Wt, convbf + L * FD, accb, partials, NN);
    k_bnred<<<256, 256, 0, stream>>>(partials, stat, NBG);
    k_bnapply<<<(NN * 64 + 255) / 256, 256, 0, stream>>>(accb, hbuf, stat, gammaf + L * FD, betaf + L * FD, NN * 64, 1.0f / NN);
  }

  k_final<<<(NN + 255) / 256, 256, 0, stream>>>((const unsigned short*)hbuf, linwf, linbf, d_out, NN, flags);
}

// Round 4
// 1425.558 us; speedup vs baseline: 3.7164x; 1.1478x over previous
//
#include <hip/hip_runtime.h>
#include <hip/hip_bf16.h>
#include <cstddef>

#define NN 50000
#define NE 600000
#define FD 128
#define NL 10
#define BN_EPS 1e-5f
#define NBG ((NN + 127) / 128)   // 391 gemm blocks
#define SCB ((NN + 255) / 256)   // 196 scan blocks

typedef _Float16 f16x8 __attribute__((ext_vector_type(8)));
typedef _Float16 f16x2 __attribute__((ext_vector_type(2)));
typedef float f32x4 __attribute__((ext_vector_type(4)));

// ---------------- dtype detection ----------------
__global__ void k_detect(const unsigned int* __restrict__ gamma_raw,
                         const unsigned int* __restrict__ idx_raw,
                         int* __restrict__ flags) {
  if (threadIdx.x == 0 && blockIdx.x == 0) {
    flags[0] = (gamma_raw[0] == 0x3F803F80u) ? 1 : 0;   // 1 = floats are bf16
    int i64 = 1;
    for (int i = 1; i < 64; i += 2)
      if (idx_raw[i] != 0u) i64 = 0;
    flags[1] = i64;                                      // 1 = indices are int64
  }
}

__device__ __forceinline__ float ld_f(const void* src, int i, int isbf) {
  if (isbf) {
    unsigned int u = ((const unsigned short*)src)[i];
    return __uint_as_float(u << 16);
  }
  return ((const float*)src)[i];
}

__global__ void k_conv_f(const void* __restrict__ src, float* __restrict__ dst,
                         int n, const int* __restrict__ flags) {
  int i = blockIdx.x * 256 + threadIdx.x;
  if (i >= n) return;
  dst[i] = ld_f(src, i, flags[0]);
}

__global__ void k_conv_i(const void* __restrict__ src, int* __restrict__ dst,
                         int n, const int* __restrict__ flags) {
  int i = blockIdx.x * 256 + threadIdx.x;
  if (i >= n) return;
  if (flags[1]) dst[i] = (int)((const long long*)src)[i];
  else          dst[i] = ((const int*)src)[i];
}

// x -> fp16 h (packed as uint half2 pairs), n2 = count of pairs
__global__ void k_conv_h(const void* __restrict__ src, unsigned int* __restrict__ dst,
                         int n2, const int* __restrict__ flags) {
  int i = blockIdx.x * 256 + threadIdx.x;
  if (i >= n2) return;
  int isbf = flags[0];
  f16x2 p;
  p.x = (_Float16)ld_f(src, i * 2, isbf);
  p.y = (_Float16)ld_f(src, i * 2 + 1, isbf);
  dst[i] = *(unsigned int*)&p;
}

// conv_w [10][4][128][128] -> fp16 tiled Wt[(L*16+s)*4096 + n*32 + kk]
//   where s = kc*4+kb, source element = W[L][kc][kb*32+kk][n]
__global__ void k_prepW(const void* __restrict__ src, unsigned short* __restrict__ dst,
                        const int* __restrict__ flags) {
  int tid = blockIdx.x * 256 + threadIdx.x;   // < 655360
  if (tid >= NL * 16 * 4096) return;
  int L = tid >> 16;
  int r16 = tid & 65535;
  int s = r16 >> 12;
  int r = r16 & 4095;
  int n = r >> 5, kk = r & 31;
  int kc = s >> 2, kb = s & 3;
  int srcIdx = ((L * 4 + kc) * FD + (kb * 32 + kk)) * FD + n;
  _Float16 v = (_Float16)ld_f(src, srcIdx, flags[0]);
  dst[tid] = *(unsigned short*)&v;
}

// ---------------- graph preprocessing ----------------
__global__ void k_deg(const int* __restrict__ src, const int* __restrict__ dst,
                      const float* __restrict__ w, float* __restrict__ deg, int m) {
  int e = blockIdx.x * 256 + threadIdx.x;
  if (e >= m) return;
  int s = src[e], d = dst[e];
  float ww = (s == d) ? 0.f : w[e];
  atomicAdd(&deg[s], ww);
}

__global__ void k_dis(float* __restrict__ deg, int n) {
  int i = blockIdx.x * 256 + threadIdx.x;
  if (i >= n) return;
  float d = deg[i];
  deg[i] = (d > 0.f) ? rsqrtf(d) : 0.f;
}

__global__ void k_norm(const int* __restrict__ src, const int* __restrict__ dst,
                       const float* __restrict__ w, const float* __restrict__ dis,
                       float* __restrict__ norm, int* __restrict__ counts, int m) {
  int e = blockIdx.x * 256 + threadIdx.x;
  if (e >= m) return;
  int s = src[e], d = dst[e];
  float ww = (s == d) ? 0.f : w[e];
  norm[e] = -dis[s] * ww * dis[d];
  atomicAdd(&counts[d], 1);
}

// ---- multi-block exclusive scan of counts -> rowptr/cursor ----
__global__ void k_scan1(const int* __restrict__ counts, int* __restrict__ bsum, int n) {
  __shared__ int sd[256];
  int i = blockIdx.x * 256 + threadIdx.x;
  sd[threadIdx.x] = (i < n) ? counts[i] : 0;
  __syncthreads();
  for (int off = 128; off; off >>= 1) {
    if (threadIdx.x < off) sd[threadIdx.x] += sd[threadIdx.x + off];
    __syncthreads();
  }
  if (threadIdx.x == 0) bsum[blockIdx.x] = sd[0];
}

__global__ void k_scan2(const int* __restrict__ bsum, int* __restrict__ boff, int nb) {
  __shared__ int sd[256];
  int t = threadIdx.x;
  int v = (t < nb) ? bsum[t] : 0;
  sd[t] = v;
  __syncthreads();
  for (int off = 1; off < 256; off <<= 1) {
    int x = sd[t];
    int add = (t >= off) ? sd[t - off] : 0;
    __syncthreads();
    sd[t] = x + add;
    __syncthreads();
  }
  if (t < nb) boff[t] = sd[t] - v;   // exclusive
}

__global__ void k_scan3(const int* __restrict__ counts, const int* __restrict__ boff,
                        int* __restrict__ rowptr, int* __restrict__ cursor, int n, int m) {
  __shared__ int sd[256];
  int t = threadIdx.x;
  int i = blockIdx.x * 256 + t;
  int v = (i < n) ? counts[i] : 0;
  sd[t] = v;
  __syncthreads();
  for (int off = 1; off < 256; off <<= 1) {
    int x = sd[t];
    int add = (t >= off) ? sd[t - off] : 0;
    __syncthreads();
    sd[t] = x + add;
    __syncthreads();
  }
  if (i < n) {
    int excl = boff[blockIdx.x] + sd[t] - v;
    rowptr[i] = excl;
    cursor[i] = excl;
  }
  if (i == n - 1) rowptr[n] = m;
}

__global__ void k_fill(const int* __restrict__ src, const int* __restrict__ dst,
                       const float* __restrict__ norm, int* __restrict__ cursor,
                       int2* __restrict__ esw, int m) {
  int e = blockIdx.x * 256 + threadIdx.x;
  if (e >= m) return;
  int d = dst[e];
  int pos = atomicAdd(&cursor[d], 1);
  esw[pos] = make_int2(src[e], __float_as_int(norm[e]));
}

// ---------------- propagate (fp16 uint2 gathers, 32 lanes/node, 8-deep) ----------------
__global__ __launch_bounds__(256) void k_prop(const uint2* __restrict__ h64,
                                              const uint2* __restrict__ prev64,
                                              const int* __restrict__ rowptr,
                                              const int2* __restrict__ esw,
                                              uint2* __restrict__ out64,
                                              float scale, int n) {
  int node = blockIdx.x * 8 + (threadIdx.x >> 5);
  int l = threadIdx.x & 31;
  if (node >= n) return;
  int beg = rowptr[node], end = rowptr[node + 1];
  float a0 = 0.f, a1 = 0.f, a2 = 0.f, a3 = 0.f;
  for (int e = beg; e < end; e += 8) {
    int   s[8];
    float w[8];
#pragma unroll
    for (int j = 0; j < 8; j++) {
      int ee = e + j;
      int ec = (ee < end) ? ee : (end - 1);
      int2 m = esw[ec];
      s[j] = m.x;
      w[j] = (ee < end) ? __int_as_float(m.y) : 0.f;
    }
    uint2 g[8];
#pragma unroll
    for (int j = 0; j < 8; j++) g[j] = h64[(size_t)s[j] * 32 + l];
#pragma unroll
    for (int j = 0; j < 8; j++) {
      f16x2 u0 = *(f16x2*)&g[j].x;
      f16x2 u1 = *(f16x2*)&g[j].y;
      a0 = fmaf(w[j], (float)u0.x, a0);
      a1 = fmaf(w[j], (float)u0.y, a1);
      a2 = fmaf(w[j], (float)u1.x, a2);
      a3 = fmaf(w[j], (float)u1.y, a3);
    }
  }
  a0 *= scale; a1 *= scale; a2 *= scale; a3 *= scale;
  if (prev64) {
    uint2 pv = prev64[(size_t)node * 32 + l];
    f16x2 p0 = *(f16x2*)&pv.x, p1 = *(f16x2*)&pv.y;
    a0 -= (float)p0.x; a1 -= (float)p0.y;
    a2 -= (float)p1.x; a3 -= (float)p1.y;
  }
  f16x2 o0, o1;
  o0.x = (_Float16)a0; o0.y = (_Float16)a1;
  o1.x = (_Float16)a2; o1.y = (_Float16)a3;
  uint2 o;
  o.x = *(unsigned int*)&o0; o.y = *(unsigned int*)&o1;
  out64[(size_t)node * 32 + l] = o;
}

// ---- MFMA fp16 GEMM: hbuf <- relu([T0|T1|T2|T3] @ Wt + b) (in place on T0), + BN partials ----
__global__ __launch_bounds__(256) void k_gemm(const unsigned short* __restrict__ T0h,
                                              const unsigned short* __restrict__ T1h,
                                              const unsigned short* __restrict__ T2h,
                                              const unsigned short* __restrict__ T3h,
                                              const unsigned short* __restrict__ Wt,
                                              const float* __restrict__ bias,
                                              unsigned short* __restrict__ outh,
                                              float* __restrict__ partials, int n) {
  __shared__ unsigned short ldsB[2][128 * 40];   // stride 40 shorts = 80B
  __shared__ float lps[4][128], lqs[4][128];
  int tid = threadIdx.x;
  int wid = tid >> 6, lane = tid & 63;
  int ln = lane & 15, kg = lane >> 4;
  int r0 = blockIdx.x * 128 + wid * 32;

  f32x4 acc[2][8];
#pragma unroll
  for (int rb = 0; rb < 2; rb++)
#pragma unroll
    for (int nb = 0; nb < 8; nb++) acc[rb][nb] = (f32x4){0.f, 0.f, 0.f, 0.f};

  {
    const uint4* g = (const uint4*)(Wt);
    uint4 a = g[tid], b = g[tid + 256];
    *(uint4*)&ldsB[0][(tid >> 2) * 40 + (tid & 3) * 8] = a;
    *(uint4*)&ldsB[0][((tid >> 2) + 64) * 40 + (tid & 3) * 8] = b;
  }
  __syncthreads();

  int rowA0 = r0 + ln;       if (rowA0 >= n) rowA0 = n - 1;
  int rowA1 = r0 + 16 + ln;  if (rowA1 >= n) rowA1 = n - 1;

#pragma unroll
  for (int kc = 0; kc < 4; ++kc) {
    const unsigned short* T = (kc == 0) ? T0h : (kc == 1) ? T1h : (kc == 2) ? T2h : T3h;
#pragma unroll
    for (int kb = 0; kb < 4; ++kb) {
      const int s = kc * 4 + kb;
      const int cur = s & 1;
      uint4 st0, st1;
      if (s < 15) {
        const uint4* g = (const uint4*)(Wt + (s + 1) * 4096);
        st0 = g[tid]; st1 = g[tid + 256];
      }
      f16x8 a0 = *(const f16x8*)(T + (size_t)rowA0 * FD + kb * 32 + kg * 8);
      f16x8 a1 = *(const f16x8*)(T + (size_t)rowA1 * FD + kb * 32 + kg * 8);
      f16x8 bf[8];
#pragma unroll
      for (int nb = 0; nb < 8; nb++)
        bf[nb] = *(const f16x8*)&ldsB[cur][(nb * 16 + ln) * 40 + kg * 8];
#pragma unroll
      for (int nb = 0; nb < 8; nb++) {
        acc[0][nb] = __builtin_amdgcn_mfma_f32_16x16x32_f16(a0, bf[nb], acc[0][nb], 0, 0, 0);
        acc[1][nb] = __builtin_amdgcn_mfma_f32_16x16x32_f16(a1, bf[nb], acc[1][nb], 0, 0, 0);
      }
      if (s < 15) {
        *(uint4*)&ldsB[cur ^ 1][(tid >> 2) * 40 + (tid & 3) * 8] = st0;
        *(uint4*)&ldsB[cur ^ 1][((tid >> 2) + 64) * 40 + (tid & 3) * 8] = st1;
      }
      __syncthreads();
    }
  }

  // epilogue: bias + relu + fp16 store (in-place safe: rows are block-private) + BN partials
  float psum[8], psq[8];
#pragma unroll
  for (int nb = 0; nb < 8; nb++) { psum[nb] = 0.f; psq[nb] = 0.f; }
#pragma unroll
  for (int rb = 0; rb < 2; rb++) {
#pragma unroll
    for (int nb = 0; nb < 8; nb++) {
      int col = nb * 16 + ln;
      float bs = bias[col];
#pragma unroll
      for (int r = 0; r < 4; r++) {
        int row = r0 + rb * 16 + kg * 4 + r;
        if (row < n) {
          float v = acc[rb][nb][r] + bs;
          v = fmaxf(v, 0.f);
          _Float16 hv = (_Float16)v;
          outh[(size_t)row * FD + col] = *(unsigned short*)&hv;
          psum[nb] += v;
          psq[nb] += v * v;
        }
      }
    }
  }
#pragma unroll
  for (int nb = 0; nb < 8; nb++) {
    float sv = psum[nb], qv = psq[nb];
    sv += __shfl_xor(sv, 16); sv += __shfl_xor(sv, 32);
    qv += __shfl_xor(qv, 16); qv += __shfl_xor(qv, 32);
    if (kg == 0) { lps[wid][nb * 16 + ln] = sv; lqs[wid][nb * 16 + ln] = qv; }
  }
  __syncthreads();
  if (tid < 128) {
    float sv = lps[0][tid] + lps[1][tid] + lps[2][tid] + lps[3][tid];
    partials[(size_t)blockIdx.x * 256 + tid] = sv;
  } else {
    int c = tid - 128;
    float qv = lqs[0][c] + lqs[1][c] + lqs[2][c] + lqs[3][c];
    partials[(size_t)blockIdx.x * 256 + 128 + c] = qv;
  }
}

__global__ void k_bnred(const float* __restrict__ partials, float* __restrict__ stat, int nblocks) {
  int c = blockIdx.x;   // 0..255
  float s = 0.f;
  for (int b = threadIdx.x; b < nblocks; b += 256) s += partials[(size_t)b * 256 + c];
  __shared__ float sd[256];
  sd[threadIdx.x] = s;
  __syncthreads();
  for (int off = 128; off; off >>= 1) {
    if (threadIdx.x < off) sd[threadIdx.x] += sd[threadIdx.x + off];
    __syncthreads();
  }
  if (threadIdx.x == 0) stat[c] = sd[0];
}

// in-place BN on fp16 hbuf
__global__ void k_bnapply(unsigned int* __restrict__ h2,
                          const float* __restrict__ stat, const float* __restrict__ gamma,
                          const float* __restrict__ beta, int n2, float invN) {
  int i = blockIdx.x * 256 + threadIdx.x;
  if (i >= n2) return;
  int f0 = (i & 63) * 2;
  unsigned int u = h2[i];
  f16x2 v = *(f16x2*)&u;
  float m0 = stat[f0] * invN;
  float m1 = stat[f0 + 1] * invN;
  float iv0 = rsqrtf(stat[128 + f0] * invN - m0 * m0 + BN_EPS);
  float iv1 = rsqrtf(stat[128 + f0 + 1] * invN - m1 * m1 + BN_EPS);
  float r0 = ((float)v.x - m0) * iv0 * gamma[f0] + beta[f0];
  float r1 = ((float)v.y - m1) * iv1 * gamma[f0 + 1] + beta[f0 + 1];
  f16x2 o; o.x = (_Float16)r0; o.y = (_Float16)r1;
  h2[i] = *(unsigned int*)&o;
}

// ---------------- final linear 128->16, one node per thread ----------------
__global__ void k_final(const unsigned short* __restrict__ h, const float* __restrict__ w,
                        const float* __restrict__ b, void* __restrict__ out,
                        int n, const int* __restrict__ flags) {
  __shared__ float lw[2048];
  for (int i = threadIdx.x; i < 2048; i += 256) lw[i] = w[i];
  __syncthreads();
  int node = blockIdx.x * 256 + threadIdx.x;
  if (node >= n) return;
  float acc[16];
#pragma unroll
  for (int c = 0; c < 16; c++) acc[c] = b[c];
  const f16x8* hr = (const f16x8*)(h + (size_t)node * FD);
#pragma unroll 2
  for (int k8 = 0; k8 < 16; k8++) {
    f16x8 hv = hr[k8];
#pragma unroll
    for (int j = 0; j < 8; j++) {
      float x = (float)hv[j];
#pragma unroll
      for (int c = 0; c < 16; c++) acc[c] = fmaf(x, lw[(k8 * 8 + j) * 16 + c], acc[c]);
    }
  }
  int isbf = flags[0];
  for (int c = 0; c < 16; c++) {
    int idx = node * 16 + c;
    if (isbf) ((__hip_bfloat16*)out)[idx] = __float2bfloat16(acc[c]);
    else      ((float*)out)[idx] = acc[c];
  }
}

// ---------------- launcher ----------------
extern "C" void kernel_launch(void* const* d_in, const int* in_sizes, int n_in,
                              void* d_out, int out_size, void* d_ws, size_t ws_size,
                              hipStream_t stream) {
  char* p = (char*)d_ws;
  auto take = [&](size_t bytes) -> void* {
    void* r = (void*)p;
    p += (bytes + 255) & ~size_t(255);
    return r;
  };
  int*   flags  = (int*)  take(64);
  int*   idx32  = (int*)  take(sizeof(int) * 2 * NE);
  float* ewf    = (float*)take(sizeof(float) * NE);
  unsigned short* wtws = (unsigned short*)take(sizeof(short) * NL * 16 * 4096);
  float* convbf = (float*)take(sizeof(float) * NL * FD);
  float* gammaf = (float*)take(sizeof(float) * NL * FD);
  float* betaf  = (float*)take(sizeof(float) * NL * FD);
  float* linwf  = (float*)take(sizeof(float) * FD * 16);
  float* linbf  = (float*)take(sizeof(float) * 16);
  float* deg    = (float*)take(sizeof(float) * NN);
  float* norm   = (float*)take(sizeof(float) * NE);
  int*   counts = (int*)  take(sizeof(int) * NN);
  int*   rowptr = (int*)  take(sizeof(int) * (NN + 1));
  int*   cursor = (int*)  take(sizeof(int) * NN);
  int*   bsum   = (int*)  take(sizeof(int) * SCB);
  int*   boff   = (int*)  take(sizeof(int) * SCB);
  int2*  esw    = (int2*) take(sizeof(int2) * NE);
  unsigned int* hbuf = (unsigned int*)take(sizeof(int) * (size_t)NN * 64);
  unsigned int* t1   = (unsigned int*)take(sizeof(int) * (size_t)NN * 64);
  unsigned int* t2   = (unsigned int*)take(sizeof(int) * (size_t)NN * 64);
  unsigned int* t3   = (unsigned int*)take(sizeof(int) * (size_t)NN * 64);
  float* partials = (float*)take(sizeof(float) * (size_t)NBG * 256);
  float* stat   = (float*)take(sizeof(float) * 256);

  k_detect<<<1, 64, 0, stream>>>((const unsigned int*)d_in[5], (const unsigned int*)d_in[1], flags);

  k_conv_i<<<(2 * NE + 255) / 256, 256, 0, stream>>>(d_in[1], idx32, 2 * NE, flags);
  k_conv_h<<<(NN * 64 + 255) / 256, 256, 0, stream>>>(d_in[0], hbuf, NN * 64, flags);
  k_conv_f<<<(NE + 255) / 256, 256, 0, stream>>>(d_in[2], ewf, NE, flags);
  k_prepW<<<(NL * 16 * 4096 + 255) / 256, 256, 0, stream>>>(d_in[3], wtws, flags);
  k_conv_f<<<(NL * FD + 255) / 256, 256, 0, stream>>>(d_in[4], convbf, NL * FD, flags);
  k_conv_f<<<(NL * FD + 255) / 256, 256, 0, stream>>>(d_in[6], betaf, NL * FD, flags);
  k_conv_f<<<(NL * FD + 255) / 256, 256, 0, stream>>>(d_in[5], gammaf, NL * FD, flags);
  k_conv_f<<<(FD * 16 + 255) / 256, 256, 0, stream>>>(d_in[7], linwf, FD * 16, flags);
  k_conv_f<<<1, 256, 0, stream>>>(d_in[8], linbf, 16, flags);

  hipMemsetAsync(deg, 0, sizeof(float) * NN, stream);
  hipMemsetAsync(counts, 0, sizeof(int) * NN, stream);

  const int* srcI = idx32;
  const int* dstI = idx32 + NE;
  k_deg<<<(NE + 255) / 256, 256, 0, stream>>>(srcI, dstI, ewf, deg, NE);
  k_dis<<<(NN + 255) / 256, 256, 0, stream>>>(deg, NN);
  k_norm<<<(NE + 255) / 256, 256, 0, stream>>>(srcI, dstI, ewf, deg, norm, counts, NE);
  k_scan1<<<SCB, 256, 0, stream>>>(counts, bsum, NN);
  k_scan2<<<1, 256, 0, stream>>>(bsum, boff, SCB);
  k_scan3<<<SCB, 256, 0, stream>>>(counts, boff, rowptr, cursor, NN, NE);
  k_fill<<<(NE + 255) / 256, 256, 0, stream>>>(srcI, dstI, norm, cursor, esw, NE);

  for (int L = 0; L < NL; ++L) {
    const unsigned short* Wt = wtws + (size_t)L * 16 * 4096;
    k_prop<<<(NN + 7) / 8, 256, 0, stream>>>((const uint2*)hbuf, nullptr, rowptr, esw, (uint2*)t1, 1.f, NN);
    k_prop<<<(NN + 7) / 8, 256, 0, stream>>>((const uint2*)t1, (const uint2*)hbuf, rowptr, esw, (uint2*)t2, 2.f, NN);
    k_prop<<<(NN + 7) / 8, 256, 0, stream>>>((const uint2*)t2, (const uint2*)t1, rowptr, esw, (uint2*)t3, 2.f, NN);
    k_gemm<<<NBG, 256, 0, stream>>>((const unsigned short*)hbuf, (const unsigned short*)t1,
                                    (const unsigned short*)t2, (const unsigned short*)t3,
                                    Wt, convbf + L * FD, (unsigned short*)hbuf, partials, NN);
    k_bnred<<<256, 256, 0, stream>>>(partials, stat, NBG);
    k_bnapply<<<(NN * 64 + 255) / 256, 256, 0, stream>>>(hbuf, stat, gammaf + L * FD, betaf + L * FD, NN * 64, 1.0f / NN);
  }

  k_final<<<(NN + 255) / 256, 256, 0, stream>>>((const unsigned short*)hbuf, linwf, linbf, d_out, NN, flags);
}